// Round 14
// baseline (1750.153 us; speedup 1.0000x reference)
//
#include <hip/hip_runtime.h>

#define Nn 4096
#define KK 20
#define BN 16384   // B*N, B=4

typedef __attribute__((ext_vector_type(8))) short bf16x8;
typedef __attribute__((ext_vector_type(4))) float f32x4;

__device__ __forceinline__ unsigned short f2bf(float f) {
  unsigned int x = __float_as_uint(f);
  return (unsigned short)((x + 0x7fffu + ((x >> 16) & 1u)) >> 16);
}
__device__ __forceinline__ float bf2f(unsigned short u) {
  return __uint_as_float(((unsigned int)u) << 16);
}

// ---------------- extract pts = x[:,:,:3] ---------------------------------
__global__ void k_pts(const float* __restrict__ x, float* __restrict__ pts) {
  int i = blockIdx.x * 256 + threadIdx.x;
  if (i < BN * 3) {
    int pt = i / 3, c = i - 3 * pt;
    pts[i] = x[pt * 6 + c];
  }
}

// ---------------- weight convert+transpose to bf16 ------------------------
__global__ void k_cvtT(const float* __restrict__ src, unsigned short* __restrict__ dst,
                       int N, int K, int ldn, int row0) {
  int i = blockIdx.x * 256 + threadIdx.x;
  if (i >= N * K) return;
  int n = i / K, k = i - n * K;
  dst[i] = f2bf(src[(size_t)(row0 + k) * ldn + n]);
}

// ---------------- transpose + 3-way bf16 split ----------------------------
__global__ void k_cvtT3(const float* __restrict__ src, unsigned short* __restrict__ h,
                        unsigned short* __restrict__ m, unsigned short* __restrict__ l,
                        int N, int K, int ldn) {
  int i = blockIdx.x * 256 + threadIdx.x;
  if (i >= N * K) return;
  int n = i / K, k = i - n * K;
  float x = src[(size_t)k * ldn + n];
  unsigned short hh = f2bf(x); float xh = bf2f(hh);
  unsigned short mm = f2bf(x - xh); float xm = bf2f(mm);
  unsigned short ll = f2bf(x - xh - xm);
  h[i] = hh; m[i] = mm; l[i] = ll;
}

// ---------------- 3-way bf16 split (row-major passthrough) ----------------
__global__ void k_split3(const float* __restrict__ src, unsigned short* __restrict__ h,
                         unsigned short* __restrict__ m, unsigned short* __restrict__ l, int n) {
  int i = blockIdx.x * 256 + threadIdx.x;
  if (i >= n) return;
  float x = src[i];
  unsigned short hh = f2bf(x); float xh = bf2f(hh);
  unsigned short mm = f2bf(x - xh); float xm = bf2f(mm);
  unsigned short ll = f2bf(x - xh - xm);
  h[i] = hh; m[i] = mm; l[i] = ll;
}

// ---------------- xcat bf16 [pt][192] = [x1|x2|x3] ------------------------
__global__ void k_cat(const float* __restrict__ x1, const float* __restrict__ x2,
                      const float* __restrict__ x3, unsigned short* __restrict__ xcat) {
  int i = blockIdx.x * 256 + threadIdx.x;
  int pt = i / 192, j = i - pt * 192;
  float v = (j < 64) ? x1[pt * 64 + j] : (j < 128 ? x2[pt * 64 + j - 64] : x3[pt * 64 + j - 128]);
  xcat[i] = f2bf(v);
}

// ---------------- shared distance helper (identical codegen both passes) --
__device__ __forceinline__ float dist4(const float4* __restrict__ tile4, int c,
                                       float qx, float qy, float qz, float qsq) {
  float4 v = tile4[c];
  float dot = fmaf(qx, v.x, fmaf(qy, v.y, qz * v.z));
  return 2.0f * dot - qsq - v.w;
}

// ---------------- kNN, C=3: 1024 thr = 16 waves = 16 queries --------------
__global__ __launch_bounds__(1024) void k_knn3(const float* __restrict__ src, int* __restrict__ idx) {
  __shared__ float4 tile4[Nn];   // 64 KB
  int t = threadIdx.x;
  int wave = t >> 6, lane = t & 63;
  int g = blockIdx.x * 16 + wave;
  int b = g >> 12, n = g & (Nn - 1);
  const float* base = src + (size_t)b * Nn * 3;
  for (int e = t; e < Nn; e += 1024) {
    float x = base[e * 3], y = base[e * 3 + 1], z = base[e * 3 + 2];
    tile4[e] = make_float4(x, y, z, fmaf(x, x, fmaf(y, y, z * z)));
  }
  __syncthreads();
  float4 q4 = tile4[n];
  float qx = q4.x, qy = q4.y, qz = q4.z, qsq = q4.w;
  float m1 = -INFINITY, m2 = -INFINITY, m3 = -INFINITY;
  int t1 = 0, t2 = 0, t3 = 0;
#pragma unroll 4
  for (int tt = 0; tt < 64; ++tt) {
    float dd = dist4(tile4, (tt << 6) + lane, qx, qy, qz, qsq);
    if (dd > m3) {
      if (dd > m1) { m3 = m2; t3 = t2; m2 = m1; t2 = t1; m1 = dd; t1 = tt; }
      else if (dd > m2) { m3 = m2; t3 = t2; m2 = dd; t2 = tt; }
      else { m3 = dd; t3 = tt; }
    }
  }
  unsigned long long removed = 0ull;
  int cnt = 3;
  int sel = 0;
#pragma unroll 1
  for (int k = 0; k < 20; ++k) {
    float v = m1; int ci = (t1 << 6) | lane;
#pragma unroll
    for (int off = 32; off; off >>= 1) {
      float ov = __shfl_xor(v, off, 64);
      int   oi = __shfl_xor(ci, off, 64);
      if (ov > v || (ov == v && oi < ci)) { v = ov; ci = oi; }
    }
    if (k == lane) sel = ci;
    if ((ci & 63) == lane && (ci >> 6) == t1) {
      removed |= 1ull << t1;
      if (cnt > 1) { m1 = m2; t1 = t2; m2 = m3; t2 = t3; --cnt; }
      else {
        m1 = -INFINITY; m2 = -INFINITY; m3 = -INFINITY; t1 = 0; t2 = 0; t3 = 0;
#pragma unroll 1
        for (int tt = 0; tt < 64; ++tt) {
          if ((removed >> tt) & 1ull) continue;
          float dd = dist4(tile4, (tt << 6) + lane, qx, qy, qz, qsq);
          if (dd > m3) {
            if (dd > m1) { m3 = m2; t3 = t2; m2 = m1; t2 = t1; m1 = dd; t1 = tt; }
            else if (dd > m2) { m3 = m2; t3 = t2; m2 = dd; t2 = tt; }
            else { m3 = dd; t3 = tt; }
          }
        }
        cnt = 3;
      }
    }
  }
  if (lane < 20) idx[(size_t)g * KK + lane] = sel;
}

// ---------------- sq norms ------------------------------------------------
__global__ void k_sqnorm(const float* __restrict__ src, float* __restrict__ out) {
  int g = blockIdx.x * 256 + threadIdx.x;
  if (g >= BN) return;
  const float4* r = (const float4*)(src + (size_t)g * 64);
  float s = 0.f;
#pragma unroll
  for (int j = 0; j < 16; ++j) { float4 v = r[j]; s += v.x * v.x + v.y * v.y + v.z * v.z + v.w * v.w; }
  out[g] = s;
}

// ---------------- distance GEMM via 3-split bf16 MFMA ---------------------
__global__ __launch_bounds__(256) void k_dist3s(const unsigned short* __restrict__ Xh,
                                                const unsigned short* __restrict__ Xm,
                                                const unsigned short* __restrict__ Xl,
                                                const float* __restrict__ sq,
                                                int b, float* __restrict__ D) {
  int t = threadIdx.x;
  int wv = t >> 6, lane = t & 63;
  int quad = lane >> 4, l16 = lane & 15;
  int wx = wv & 1, wy = wv >> 1;
  int bx = blockIdx.x & 63, by = blockIdx.x >> 6;
  const size_t base = (size_t)b * Nn * 64;
  int ra0 = by * 64 + wy * 32;
  int cb0 = bx * 64 + wx * 32;
  f32x4 acc[2][2];
  f32x4 zz = {0.f, 0.f, 0.f, 0.f};
#pragma unroll
  for (int i = 0; i < 2; ++i)
#pragma unroll
    for (int j = 0; j < 2; ++j) acc[i][j] = zz;
#pragma unroll
  for (int ks = 0; ks < 2; ++ks) {
    int ko = ks * 32 + quad * 8;
    bf16x8 ah[2], am[2], al[2], bh[2], bm[2], bl[2];
#pragma unroll
    for (int ti = 0; ti < 2; ++ti) {
      size_t ra = base + (size_t)(ra0 + ti * 16 + l16) * 64 + ko;
      ah[ti] = *(const bf16x8*)(Xh + ra);
      am[ti] = *(const bf16x8*)(Xm + ra);
      al[ti] = *(const bf16x8*)(Xl + ra);
      size_t rb = base + (size_t)(cb0 + ti * 16 + l16) * 64 + ko;
      bh[ti] = *(const bf16x8*)(Xh + rb);
      bm[ti] = *(const bf16x8*)(Xm + rb);
      bl[ti] = *(const bf16x8*)(Xl + rb);
    }
#pragma unroll
    for (int ti = 0; ti < 2; ++ti)
#pragma unroll
      for (int tj = 0; tj < 2; ++tj) {
        f32x4 a = acc[ti][tj];
        a = __builtin_amdgcn_mfma_f32_16x16x32_bf16(ah[ti], bh[tj], a, 0, 0, 0);
        a = __builtin_amdgcn_mfma_f32_16x16x32_bf16(ah[ti], bm[tj], a, 0, 0, 0);
        a = __builtin_amdgcn_mfma_f32_16x16x32_bf16(am[ti], bh[tj], a, 0, 0, 0);
        a = __builtin_amdgcn_mfma_f32_16x16x32_bf16(ah[ti], bl[tj], a, 0, 0, 0);
        a = __builtin_amdgcn_mfma_f32_16x16x32_bf16(al[ti], bh[tj], a, 0, 0, 0);
        a = __builtin_amdgcn_mfma_f32_16x16x32_bf16(am[ti], bm[tj], a, 0, 0, 0);
        acc[ti][tj] = a;
      }
  }
  const float* sqb = sq + b * Nn;
#pragma unroll
  for (int ti = 0; ti < 2; ++ti) {
    int row0 = ra0 + ti * 16 + quad * 4;
#pragma unroll
    for (int tj = 0; tj < 2; ++tj) {
      int col = cb0 + tj * 16 + l16;
      float sqc = sqb[col];
#pragma unroll
      for (int r = 0; r < 4; ++r)
        D[(size_t)(row0 + r) * 4096 + col] = 2.0f * acc[ti][tj][r] - sqb[row0 + r] - sqc;
    }
  }
}

// ---------------- top-20 over D rows (d[64] cached in VGPRs) --------------
__device__ __forceinline__ int gi_map(int tt, int lane) {
  return ((tt >> 2) << 8) | (lane << 2) | (tt & 3);
}
__device__ __forceinline__ void topk_select2(const float (&d)[64], float m1, int t1, float m2, int t2,
                                             int lane, int* __restrict__ op) {
  unsigned long long removed = 0ull;
  bool have2 = true;
  int sel = 0;
#pragma unroll 1
  for (int k = 0; k < 20; ++k) {
    float v = m1; int ci = gi_map(t1, lane);
#pragma unroll
    for (int off = 32; off; off >>= 1) {
      float ov = __shfl_xor(v, off, 64);
      int   oi = __shfl_xor(ci, off, 64);
      if (ov > v || (ov == v && oi < ci)) { v = ov; ci = oi; }
    }
    if (k == lane) sel = ci;
    if (ci == gi_map(t1, lane)) {
      removed |= 1ull << t1;
      if (have2) { m1 = m2; t1 = t2; have2 = false; }
      else {
        m1 = -INFINITY; t1 = 0; m2 = -INFINITY; t2 = 0;
#pragma unroll
        for (int tt = 0; tt < 64; ++tt) {
          if (!((removed >> tt) & 1ull)) {
            float dv = d[tt];
            if (dv > m1) { m2 = m1; t2 = t1; m1 = dv; t1 = tt; }
            else if (dv > m2) { m2 = dv; t2 = tt; }
          }
        }
        have2 = true;
      }
    }
  }
  if (lane < 20) op[lane] = sel;
}

__global__ __launch_bounds__(256) void k_sel(const float* __restrict__ D, int b, int* __restrict__ idx) {
  int t = threadIdx.x;
  int wave = t >> 6, lane = t & 63;
  int q = blockIdx.x * 4 + wave;
  const float* row = D + (size_t)q * 4096;
  float d[64];
  float m1 = -INFINITY, m2 = -INFINITY; int t1 = 0, t2 = 0;
#pragma unroll
  for (int i = 0; i < 16; ++i) {
    float4 v = *(const float4*)(row + i * 256 + lane * 4);
    float vv[4] = {v.x, v.y, v.z, v.w};
#pragma unroll
    for (int j = 0; j < 4; ++j) {
      int tt = i * 4 + j;
      float dd = vv[j];
      d[tt] = dd;
      if (dd > m1) { m2 = m1; t2 = t1; m1 = dd; t1 = tt; }
      else if (dd > m2) { m2 = dd; t2 = tt; }
    }
  }
  topk_select2(d, m1, t1, m2, t2, lane, idx + (size_t)(b * Nn + q) * KK);
}

// ---------------- u/v from pts (6->64 conv1 factorized) -------------------
__global__ __launch_bounds__(256) void k_uv3(const float* __restrict__ pts, const float* __restrict__ w1,
                                             const float* __restrict__ b1, float* __restrict__ uvb) {
  __shared__ float sw[384];
  __shared__ float sb[64];
  int t = threadIdx.x;
  for (int e = t; e < 384; e += 256) sw[e] = w1[e];
  if (t < 64) sb[t] = b1[t];
  __syncthreads();
  int pl = t >> 6, c = t & 63;
  int p = blockIdx.x * 4 + pl;
  const float* pr = pts + (size_t)p * 3;
  float x0 = pr[0], x1 = pr[1], x2 = pr[2];
  float wb0 = sw[192 + c], wb1 = sw[256 + c], wb2 = sw[320 + c];
  float v = x0 * wb0 + x1 * wb1 + x2 * wb2;
  float u = sb[c] + x0 * (sw[c] - wb0) + x1 * (sw[64 + c] - wb1) + x2 * (sw[128 + c] - wb2);
  uvb[(size_t)p * 128 + c] = u;
  uvb[(size_t)p * 128 + 64 + c] = v;
}

// ---------------- prep: Md[64][128] = [Wa-Wb | Wb] from 128x64 w1 ---------
__global__ void k_prepD(const float* __restrict__ w1, float* __restrict__ Md) {
  int i = blockIdx.x * 256 + threadIdx.x;
  if (i >= 8192) return;
  int j = i >> 7, c = i & 127;
  Md[i] = (c < 64) ? (w1[j * 64 + c] - w1[(64 + j) * 64 + c]) : w1[(64 + j) * 64 + (c - 64)];
}

// ---------------- uv = x @ Md (+bias on u half) ---------------------------
__global__ __launch_bounds__(256) void k_uv(const float* __restrict__ x2, const float* __restrict__ Md,
                                            const float* __restrict__ bias, float* __restrict__ uv) {
  __shared__ float sM[8192];     // 64x128
  __shared__ float sx[64 * 68];
  int t = threadIdx.x;
  for (int e = t; e < 8192; e += 256) sM[e] = Md[e];
  int p0 = blockIdx.x * 64;
  for (int e = t; e < 1024; e += 256) {
    int r = e >> 4, c4 = e & 15;
    *(float4*)(sx + r * 68 + c4 * 4) = *(const float4*)(x2 + (size_t)(p0 + r) * 64 + c4 * 4);
  }
  __syncthreads();
  int c = t & 127, rg = t >> 7;
  float badd = (c < 64) ? bias[c] : 0.f;
  float accv[32];
#pragma unroll
  for (int r = 0; r < 32; ++r) accv[r] = 0.f;
#pragma unroll
  for (int jc = 0; jc < 8; ++jc) {
    float mreg[8];
#pragma unroll
    for (int q = 0; q < 8; ++q) mreg[q] = sM[(jc * 8 + q) * 128 + c];
#pragma unroll
    for (int r = 0; r < 32; ++r) {
      const float* xr = sx + (rg * 32 + r) * 68 + jc * 8;
      float4 a = *(const float4*)xr, bb = *(const float4*)(xr + 4);
      float s = accv[r];
      s = fmaf(a.x, mreg[0], s); s = fmaf(a.y, mreg[1], s);
      s = fmaf(a.z, mreg[2], s); s = fmaf(a.w, mreg[3], s);
      s = fmaf(bb.x, mreg[4], s); s = fmaf(bb.y, mreg[5], s);
      s = fmaf(bb.z, mreg[6], s); s = fmaf(bb.w, mreg[7], s);
      accv[r] = s;
    }
  }
#pragma unroll
  for (int r = 0; r < 32; ++r)
    uv[(size_t)(p0 + rg * 32 + r) * 128 + c] = accv[r] + badd;
}

// ---------------- per-edge conv2 via 3-split MFMA + max over edges --------
// R14: __launch_bounds__(256,4) — LDS already caps at 4 blocks/CU (= 4
// waves/SIMD), so raise the VGPR budget to 128 and let the compiler keep
// all 20 gather loads in flight (R13: VGPR=52 serialized them; block stall
// was ~30x its compute).
template <int NOUT>
__global__ __launch_bounds__(256, 4) void k_econv(const float* __restrict__ uv,
                                                  const int* __restrict__ idx,
                                                  const unsigned short* __restrict__ W2h,
                                                  const unsigned short* __restrict__ W2m,
                                                  const unsigned short* __restrict__ W2l,
                                                  const float* __restrict__ b2,
                                                  float* __restrict__ outp) {
  __shared__ unsigned short y3[4][3][20 * 72];        // 34560 B
  __shared__ __align__(16) unsigned short zrow[72];   // shared zero row
  int t = threadIdx.x;
  int wv = t >> 6, lane = t & 63;
  int quad = lane >> 4, l16 = lane & 15;
  int p = blockIdx.x * 4 + wv;
  size_t nbase = (size_t)(p >> 12) * Nn;
  const int* ip = idx + (size_t)p * KK;
  float u = uv[(size_t)p * 128 + lane];
  if (t < 72) zrow[t] = 0;
  unsigned short* yh = y3[wv][0];
  unsigned short* ym = y3[wv][1];
  unsigned short* yl = y3[wv][2];
  // hoist all 20 gathers (independent; needs the bigger VGPR budget)
  float vv[20];
#pragma unroll
  for (int k = 0; k < 20; ++k) {
    int nb = ip[k];
    vv[k] = uv[(nbase + nb) * 128 + 64 + lane];
  }
#pragma unroll
  for (int k = 0; k < 20; ++k) {
    float y = fmaxf(u + vv[k], 0.f);
    unsigned short hh = f2bf(y); float fh = bf2f(hh);
    unsigned short mm = f2bf(y - fh); float fm = bf2f(mm);
    unsigned short ll = f2bf(y - fh - fm);
    yh[k * 72 + lane] = hh;
    ym[k * 72 + lane] = mm;
    yl[k * 72 + lane] = ll;
  }
  __syncthreads();
  bf16x8 af[2][2][3];
#pragma unroll
  for (int mt = 0; mt < 2; ++mt)
#pragma unroll
    for (int ks = 0; ks < 2; ++ks) {
      int row = mt * 16 + l16;
      int ko = ks * 32 + quad * 8;
      const unsigned short* ph = (row < 20) ? (yh + row * 72) : zrow;
      const unsigned short* pm = (row < 20) ? (ym + row * 72) : zrow;
      const unsigned short* pl = (row < 20) ? (yl + row * 72) : zrow;
      af[mt][ks][0] = *(const bf16x8*)(ph + ko);
      af[mt][ks][1] = *(const bf16x8*)(pm + ko);
      af[mt][ks][2] = *(const bf16x8*)(pl + ko);
    }
#pragma unroll 1
  for (int nt = 0; nt < NOUT / 16; ++nt) {
    int col = nt * 16 + l16;
    f32x4 a0 = {0.f, 0.f, 0.f, 0.f}, a1 = {0.f, 0.f, 0.f, 0.f};
#pragma unroll
    for (int ks = 0; ks < 2; ++ks) {
      size_t wo = (size_t)col * 64 + ks * 32 + quad * 8;
      bf16x8 wh = *(const bf16x8*)(W2h + wo);
      bf16x8 wm = *(const bf16x8*)(W2m + wo);
      bf16x8 wl = *(const bf16x8*)(W2l + wo);
      a0 = __builtin_amdgcn_mfma_f32_16x16x32_bf16(af[0][ks][0], wh, a0, 0, 0, 0);
      a0 = __builtin_amdgcn_mfma_f32_16x16x32_bf16(af[0][ks][0], wm, a0, 0, 0, 0);
      a0 = __builtin_amdgcn_mfma_f32_16x16x32_bf16(af[0][ks][1], wh, a0, 0, 0, 0);
      a0 = __builtin_amdgcn_mfma_f32_16x16x32_bf16(af[0][ks][0], wl, a0, 0, 0, 0);
      a0 = __builtin_amdgcn_mfma_f32_16x16x32_bf16(af[0][ks][2], wh, a0, 0, 0, 0);
      a0 = __builtin_amdgcn_mfma_f32_16x16x32_bf16(af[0][ks][1], wm, a0, 0, 0, 0);
      a1 = __builtin_amdgcn_mfma_f32_16x16x32_bf16(af[1][ks][0], wh, a1, 0, 0, 0);
      a1 = __builtin_amdgcn_mfma_f32_16x16x32_bf16(af[1][ks][0], wm, a1, 0, 0, 0);
      a1 = __builtin_amdgcn_mfma_f32_16x16x32_bf16(af[1][ks][1], wh, a1, 0, 0, 0);
      a1 = __builtin_amdgcn_mfma_f32_16x16x32_bf16(af[1][ks][0], wl, a1, 0, 0, 0);
      a1 = __builtin_amdgcn_mfma_f32_16x16x32_bf16(af[1][ks][2], wh, a1, 0, 0, 0);
      a1 = __builtin_amdgcn_mfma_f32_16x16x32_bf16(af[1][ks][1], wm, a1, 0, 0, 0);
    }
    float m0 = fmaxf(fmaxf(a0[0], a0[1]), fmaxf(a0[2], a0[3]));
    float m1v = (quad == 0) ? fmaxf(fmaxf(a1[0], a1[1]), fmaxf(a1[2], a1[3])) : -INFINITY;
    float m = fmaxf(m0, m1v);
    m = fmaxf(m, __shfl_xor(m, 16, 64));
    m = fmaxf(m, __shfl_xor(m, 32, 64));
    if (quad == 0) outp[(size_t)p * NOUT + col] = fmaxf(m + b2[col], 0.f);
  }
}

// ---------------- x3 = relu(u + max_k v_nk)  (bias folded into u) ---------
__global__ __launch_bounds__(256) void k_gmax(const float* __restrict__ uv, const int* __restrict__ idx,
                                              float* __restrict__ x3) {
  __shared__ int sidx[4][20];
  int t = threadIdx.x;
  int pl = t >> 6, c = t & 63;
  int p0 = blockIdx.x * 4;
  if (t < 80) sidx[t / 20][t % 20] = idx[(size_t)(p0 + t / 20) * KK + (t % 20)];
  __syncthreads();
  int p = p0 + pl;
  size_t nbase = (size_t)(p >> 12) * Nn;
  float u = uv[(size_t)p * 128 + c];
  float m = -INFINITY;
#pragma unroll
  for (int k = 0; k < 20; ++k) m = fmaxf(m, uv[(nbase + sidx[pl][k]) * 128 + 64 + c]);
  x3[(size_t)p * 64 + c] = fmaxf(u + m, 0.f);
}

// ---------------- reduce partials + fc1 -----------------------------------
__global__ __launch_bounds__(256) void k_fc1(const float* __restrict__ dpart, const float* __restrict__ tb3,
                                             const float* __restrict__ tfw1, const float* __restrict__ tfb1,
                                             float* __restrict__ h1) {
  __shared__ float tv[1024];
  __shared__ float ps[256];
  int t = threadIdx.x;
  int b = blockIdx.x >> 3, cb = blockIdx.x & 7;
  for (int e = t; e < 1024; e += 256) {
    float m = -INFINITY;
#pragma unroll
    for (int s = 0; s < 8; ++s) m = fmaxf(m, dpart[((size_t)b * 8 + s) * 1024 + e]);
    tv[e] = fmaxf(m + tb3[e], 0.f);
  }
  __syncthreads();
  int c = cb * 64 + (t & 63), jg = t >> 6;
  float acc = 0.f;
  for (int j = jg * 256; j < jg * 256 + 256; ++j) acc = fmaf(tv[j], tfw1[(size_t)j * 512 + c], acc);
  ps[t] = acc;
  __syncthreads();
  if (t < 64) {
    float a = ps[t] + ps[64 + t] + ps[128 + t] + ps[192 + t] + tfb1[cb * 64 + t];
    h1[(size_t)b * 512 + cb * 64 + t] = fmaxf(a, 0.f);
  }
}

// ---------------- fc2, fc3, apply p = pts @ xf ----------------------------
__global__ __launch_bounds__(256) void k_fc23p(const float* __restrict__ h1, const float* __restrict__ tfw2,
                                               const float* __restrict__ tfb2, const float* __restrict__ txw,
                                               const float* __restrict__ txb, const float* __restrict__ pts,
                                               float* __restrict__ p) {
  __shared__ float sh1[512];
  __shared__ float h2[256];
  __shared__ float sxf[9];
  int t = threadIdx.x;
  int b = blockIdx.x;
  for (int e = t; e < 512; e += 256) sh1[e] = h1[(size_t)b * 512 + e];
  __syncthreads();
  {
    float acc = tfb2[t];
    for (int j = 0; j < 512; ++j) acc = fmaf(sh1[j], tfw2[(size_t)j * 256 + t], acc);
    h2[t] = fmaxf(acc, 0.f);
  }
  __syncthreads();
  if (t < 9) {
    float acc = txb[t];
    for (int j = 0; j < 256; ++j) acc = fmaf(h2[j], txw[j * 9 + t], acc);
    sxf[t] = acc;
  }
  __syncthreads();
  for (int n = t; n < Nn; n += 256) {
    const float* pr = pts + ((size_t)b * Nn + n) * 3;
    float a0 = pr[0], a1 = pr[1], a2 = pr[2];
    float* po = p + ((size_t)b * Nn + n) * 3;
#pragma unroll
    for (int d = 0; d < 3; ++d) po[d] = a0 * sxf[d] + a1 * sxf[3 + d] + a2 * sxf[6 + d];
  }
}

// ---------------- MFMA max-GEMM (bf16, post-kNN path) ---------------------
template <int K>
__global__ __launch_bounds__(256) void k_mgemm(const unsigned short* __restrict__ A,
                                               const unsigned short* __restrict__ WT,
                                               float* __restrict__ outp) {
  constexpr int KS = K / 32;
  int t = threadIdx.x;
  int wv = t >> 6, lane = t & 63;
  int quad = lane >> 4, l16 = lane & 15;
  int blk = blockIdx.x;
  int b = blk >> 7, cb = (blk >> 3) & 15, ns = blk & 7;
  int n0 = cb * 64 + wv * 16;
  bf16x8 bfr[KS];
  const unsigned short* wrow = WT + (size_t)(n0 + l16) * K + quad * 8;
#pragma unroll
  for (int s = 0; s < KS; ++s) bfr[s] = *(const bf16x8*)(wrow + s * 32);
  const unsigned short* Ab = A + ((size_t)b * Nn + ns * 512 + l16) * K + quad * 8;
  float rmax = -INFINITY;
#pragma unroll 2
  for (int mt = 0; mt < 32; ++mt) {
    const unsigned short* ar = Ab + (size_t)mt * 16 * K;
    f32x4 acc = {0.f, 0.f, 0.f, 0.f};
#pragma unroll
    for (int s = 0; s < KS; ++s) {
      bf16x8 af = *(const bf16x8*)(ar + s * 32);
      acc = __builtin_amdgcn_mfma_f32_16x16x32_bf16(af, bfr[s], acc, 0, 0, 0);
    }
    rmax = fmaxf(rmax, fmaxf(fmaxf(acc[0], acc[1]), fmaxf(acc[2], acc[3])));
  }
  rmax = fmaxf(rmax, __shfl_xor(rmax, 16, 64));
  rmax = fmaxf(rmax, __shfl_xor(rmax, 32, 64));
  if (quad == 0) outp[((size_t)b * 8 + ns) * 1024 + n0 + l16] = rmax;
}

// ---------------- MFMA max-GEMM, 3-split exact (t128 @ w3) ----------------
template <int K>
__global__ __launch_bounds__(256) void k_mgemm3s(const unsigned short* __restrict__ Ah,
                                                 const unsigned short* __restrict__ Am,
                                                 const unsigned short* __restrict__ Al,
                                                 const unsigned short* __restrict__ Bh,
                                                 const unsigned short* __restrict__ Bm,
                                                 const unsigned short* __restrict__ Bl,
                                                 float* __restrict__ outp) {
  constexpr int KS = K / 32;
  int t = threadIdx.x;
  int wv = t >> 6, lane = t & 63;
  int quad = lane >> 4, l16 = lane & 15;
  int blk = blockIdx.x;
  int b = blk >> 7, cb = (blk >> 3) & 15, ns = blk & 7;
  int n0 = cb * 64 + wv * 16;
  bf16x8 wh[KS], wm[KS], wl[KS];
  size_t wo = (size_t)(n0 + l16) * K + quad * 8;
#pragma unroll
  for (int s = 0; s < KS; ++s) {
    wh[s] = *(const bf16x8*)(Bh + wo + s * 32);
    wm[s] = *(const bf16x8*)(Bm + wo + s * 32);
    wl[s] = *(const bf16x8*)(Bl + wo + s * 32);
  }
  size_t ao = ((size_t)b * Nn + ns * 512 + l16) * K + quad * 8;
  float rmax = -INFINITY;
#pragma unroll 1
  for (int mt = 0; mt < 32; ++mt) {
    size_t ar = ao + (size_t)mt * 16 * K;
    f32x4 acc = {0.f, 0.f, 0.f, 0.f};
#pragma unroll
    for (int s = 0; s < KS; ++s) {
      bf16x8 xh = *(const bf16x8*)(Ah + ar + s * 32);
      bf16x8 xm = *(const bf16x8*)(Am + ar + s * 32);
      bf16x8 xl = *(const bf16x8*)(Al + ar + s * 32);
      acc = __builtin_amdgcn_mfma_f32_16x16x32_bf16(xh, wh[s], acc, 0, 0, 0);
      acc = __builtin_amdgcn_mfma_f32_16x16x32_bf16(xh, wm[s], acc, 0, 0, 0);
      acc = __builtin_amdgcn_mfma_f32_16x16x32_bf16(xm, wh[s], acc, 0, 0, 0);
      acc = __builtin_amdgcn_mfma_f32_16x16x32_bf16(xh, wl[s], acc, 0, 0, 0);
      acc = __builtin_amdgcn_mfma_f32_16x16x32_bf16(xl, wh[s], acc, 0, 0, 0);
      acc = __builtin_amdgcn_mfma_f32_16x16x32_bf16(xm, wm[s], acc, 0, 0, 0);
    }
    rmax = fmaxf(rmax, fmaxf(fmaxf(acc[0], acc[1]), fmaxf(acc[2], acc[3])));
  }
  rmax = fmaxf(rmax, __shfl_xor(rmax, 16, 64));
  rmax = fmaxf(rmax, __shfl_xor(rmax, 32, 64));
  if (quad == 0) outp[((size_t)b * 8 + ns) * 1024 + n0 + l16] = rmax;
}

// ---------------- gc = relu(max+b) @ c2w[:1024] (fp32) --------------------
__global__ __launch_bounds__(256) void k_j2(const float* __restrict__ gpart, const float* __restrict__ c1b,
                                            const float* __restrict__ c2w, float* __restrict__ gc) {
  __shared__ float g[1024];
  int t = threadIdx.x;
  int b = blockIdx.x >> 1, half = blockIdx.x & 1;
  for (int e = t; e < 1024; e += 256) {
    float m = -INFINITY;
#pragma unroll
    for (int s = 0; s < 8; ++s) m = fmaxf(m, gpart[((size_t)b * 8 + s) * 1024 + e]);
    g[e] = fmaxf(m + c1b[e], 0.f);
  }
  __syncthreads();
  int d = half * 256 + t;
  float acc = 0.f;
  for (int j = 0; j < 1024; ++j) acc = fmaf(g[j], c2w[(size_t)j * 512 + d], acc);
  gc[(size_t)b * 512 + d] = acc;
}

// ---------------- fused MFMA head: 192->512->256->2 per 16 points ---------
__global__ __launch_bounds__(256) void k_final(const unsigned short* __restrict__ xcat,
                                               const float* __restrict__ gc,
                                               const float* __restrict__ c2b,
                                               const unsigned short* __restrict__ c2wT,
                                               const unsigned short* __restrict__ c3wT,
                                               const float* __restrict__ c3b,
                                               const float* __restrict__ c4w, const float* __restrict__ c4b,
                                               float* __restrict__ out) {
  __shared__ unsigned short z5[16 * 520];
  __shared__ float z2[16 * 260];
  int t = threadIdx.x;
  int wv = t >> 6, lane = t & 63;
  int quad = lane >> 4, l16 = lane & 15;
  int p0 = blockIdx.x * 16;
  int b = p0 >> 12;
  bf16x8 a1[6];
  const unsigned short* ar = xcat + (size_t)(p0 + l16) * 192 + quad * 8;
#pragma unroll
  for (int s = 0; s < 6; ++s) a1[s] = *(const bf16x8*)(ar + s * 32);
#pragma unroll 1
  for (int ntw = 0; ntw < 8; ++ntw) {
    int col = wv * 128 + ntw * 16 + l16;
    float bias = gc[(size_t)b * 512 + col] + c2b[col];
    f32x4 acc = {bias, bias, bias, bias};
    const unsigned short* wr = c2wT + (size_t)col * 192 + quad * 8;
#pragma unroll
    for (int s = 0; s < 6; ++s) {
      bf16x8 bfr = *(const bf16x8*)(wr + s * 32);
      acc = __builtin_amdgcn_mfma_f32_16x16x32_bf16(a1[s], bfr, acc, 0, 0, 0);
    }
#pragma unroll
    for (int r = 0; r < 4; ++r)
      z5[(quad * 4 + r) * 520 + col] = f2bf(fmaxf(acc[r], 0.f));
  }
  __syncthreads();
  bf16x8 a2[16];
#pragma unroll
  for (int s = 0; s < 16; ++s) a2[s] = *(const bf16x8*)(z5 + l16 * 520 + s * 32 + quad * 8);
#pragma unroll 1
  for (int ntw = 0; ntw < 4; ++ntw) {
    int col = wv * 64 + ntw * 16 + l16;
    float bias = c3b[col];
    f32x4 acc = {bias, bias, bias, bias};
    const unsigned short* wr = c3wT + (size_t)col * 512 + quad * 8;
#pragma unroll
    for (int s = 0; s < 16; ++s) {
      bf16x8 bfr = *(const bf16x8*)(wr + s * 32);
      acc = __builtin_amdgcn_mfma_f32_16x16x32_bf16(a2[s], bfr, acc, 0, 0, 0);
    }
#pragma unroll
    for (int r = 0; r < 4; ++r)
      z2[(quad * 4 + r) * 260 + col] = fmaxf(acc[r], 0.f);
  }
  __syncthreads();
  if (t < 32) {
    int m = t >> 1, e = t & 1;
    float acc = c4b[e];
    const float* zr = z2 + m * 260;
    for (int j = 0; j < 256; ++j) acc = fmaf(zr[j], c4w[j * 2 + e], acc);
    out[(size_t)(p0 + m) * 2 + e] = acc;
  }
}

// ===========================================================================
extern "C" void kernel_launch(void* const* d_in, const int* in_sizes, int n_in,
                              void* d_out, int out_size, void* d_ws, size_t ws_size,
                              hipStream_t stream) {
  const float* xin = (const float*)d_in[0];
  const float* W[30];
  for (int i = 0; i < 30; ++i) W[i] = (const float*)d_in[i + 1];

  float* ws = (float*)d_ws;
  size_t off = 0;
  float* pts   = ws + off; off += (size_t)BN * 3;
  float* p     = ws + off; off += (size_t)BN * 3;
  int*   idx   = (int*)(ws + off); off += (size_t)BN * KK;
  float* sq    = ws + off; off += BN;
  float* t128  = ws + off; off += (size_t)BN * 128;
  float* dpart = ws + off; off += 4 * 8 * 1024;
  float* h1    = ws + off; off += 4 * 512;
  float* x1    = ws + off; off += (size_t)BN * 64;
  float* x2    = ws + off; off += (size_t)BN * 64;
  float* x3    = ws + off; off += (size_t)BN * 64;
  float* gpart = ws + off; off += 4 * 8 * 1024;
  float* gc    = ws + off; off += 4 * 512;
  float* uvb   = ws + off; off += (size_t)BN * 128;                 // u/v buffer
  unsigned short* xcat = (unsigned short*)(ws + off); off += (size_t)BN * 96;
  unsigned short* c1wT = (unsigned short*)(ws + off); off += 98304;
  unsigned short* c2wT = (unsigned short*)(ws + off); off += 49152;
  unsigned short* c3wT = (unsigned short*)(ws + off); off += 65536;
  unsigned short* w3Th = (unsigned short*)(ws + off); off += 65536;
  unsigned short* w3Tm = (unsigned short*)(ws + off); off += 65536;
  unsigned short* w3Tl = (unsigned short*)(ws + off); off += 65536;
  unsigned short* tw2h = (unsigned short*)(ws + off); off += 4096;  // 128x64 bf16
  unsigned short* tw2m = (unsigned short*)(ws + off); off += 4096;
  unsigned short* tw2l = (unsigned short*)(ws + off); off += 4096;
  unsigned short* e1h  = (unsigned short*)(ws + off); off += 2048;  // 64x64 bf16
  unsigned short* e1m  = (unsigned short*)(ws + off); off += 2048;
  unsigned short* e1l  = (unsigned short*)(ws + off); off += 2048;
  unsigned short* e2h  = (unsigned short*)(ws + off); off += 2048;
  unsigned short* e2m  = (unsigned short*)(ws + off); off += 2048;
  unsigned short* e2l  = (unsigned short*)(ws + off); off += 2048;
  unsigned short* xsh  = (unsigned short*)(ws + off); off += 524288;
  unsigned short* xsm  = (unsigned short*)(ws + off); off += 524288;
  unsigned short* xsl  = (unsigned short*)(ws + off); off += 524288;
  float* MdC   = ws + off; off += 8192;
  float* MdD   = ws + off; off += 8192;
  float* Dbuf  = ws + off; off += (size_t)Nn * Nn;
  unsigned short* t3h = (unsigned short*)Dbuf;
  unsigned short* t3m = t3h + (size_t)BN * 128;
  unsigned short* t3l = t3m + (size_t)BN * 128;

  // weight prep
  k_cvtT<<<dim3(768), dim3(256), 0, stream>>>(W[22], c1wT, 1024, 192, 1024, 0);
  k_cvtT<<<dim3(384), dim3(256), 0, stream>>>(W[24], c2wT, 512, 192, 512, 1024);
  k_cvtT<<<dim3(512), dim3(256), 0, stream>>>(W[26], c3wT, 256, 512, 256, 0);
  k_cvtT3<<<dim3(512), dim3(256), 0, stream>>>(W[4], w3Th, w3Tm, w3Tl, 1024, 128, 1024);
  k_cvtT3<<<dim3(32), dim3(256), 0, stream>>>(W[2], tw2h, tw2m, tw2l, 128, 64, 128);
  k_cvtT3<<<dim3(16), dim3(256), 0, stream>>>(W[14], e1h, e1m, e1l, 64, 64, 64);
  k_cvtT3<<<dim3(16), dim3(256), 0, stream>>>(W[18], e2h, e2m, e2l, 64, 64, 64);
  k_prepD<<<dim3(32), dim3(256), 0, stream>>>(W[16], MdC);
  k_prepD<<<dim3(32), dim3(256), 0, stream>>>(W[20], MdD);

  k_pts<<<dim3(192), dim3(256), 0, stream>>>(xin, pts);

  // stage 1: transform branch
  k_knn3<<<dim3(1024), dim3(1024), 0, stream>>>(pts, idx);
  k_uv3<<<dim3(4096), dim3(256), 0, stream>>>(pts, W[0], W[1], uvb);
  k_econv<128><<<dim3(4096), dim3(256), 0, stream>>>(uvb, idx, tw2h, tw2m, tw2l, W[3], t128);
  k_split3<<<dim3(8192), dim3(256), 0, stream>>>(t128, t3h, t3m, t3l, BN * 128);
  k_mgemm3s<128><<<dim3(512), dim3(256), 0, stream>>>(t3h, t3m, t3l, w3Th, w3Tm, w3Tl, dpart);
  k_fc1<<<dim3(32), dim3(256), 0, stream>>>(dpart, W[5], W[6], W[7], h1);
  k_fc23p<<<dim3(4), dim3(256), 0, stream>>>(h1, W[8], W[9], W[10], W[11], pts, p);

  // stage 2
  k_knn3<<<dim3(1024), dim3(1024), 0, stream>>>(p, idx);
  k_uv3<<<dim3(4096), dim3(256), 0, stream>>>(p, W[12], W[13], uvb);
  k_econv<64><<<dim3(4096), dim3(256), 0, stream>>>(uvb, idx, e1h, e1m, e1l, W[15], x1);
  k_sqnorm<<<dim3(64), dim3(256), 0, stream>>>(x1, sq);
  k_split3<<<dim3(4096), dim3(256), 0, stream>>>(x1, xsh, xsm, xsl, BN * 64);
  for (int b = 0; b < 4; ++b) {
    k_dist3s<<<dim3(4096), dim3(256), 0, stream>>>(xsh, xsm, xsl, sq, b, Dbuf);
    k_sel<<<dim3(1024), dim3(256), 0, stream>>>(Dbuf, b, idx);
  }
  k_uv<<<dim3(256), dim3(256), 0, stream>>>(x1, MdC, W[17], uvb);
  k_econv<64><<<dim3(4096), dim3(256), 0, stream>>>(uvb, idx, e2h, e2m, e2l, W[19], x2);
  k_sqnorm<<<dim3(64), dim3(256), 0, stream>>>(x2, sq);
  k_split3<<<dim3(4096), dim3(256), 0, stream>>>(x2, xsh, xsm, xsl, BN * 64);
  for (int b = 0; b < 4; ++b) {
    k_dist3s<<<dim3(4096), dim3(256), 0, stream>>>(xsh, xsm, xsl, sq, b, Dbuf);
    k_sel<<<dim3(1024), dim3(256), 0, stream>>>(Dbuf, b, idx);
  }
  // edgeD via u/v factorization (bias folded into u)
  k_uv<<<dim3(256), dim3(256), 0, stream>>>(x2, MdD, W[21], uvb);
  k_gmax<<<dim3(4096), dim3(256), 0, stream>>>(uvb, idx, x3);

  // stage 3
  k_cat<<<dim3(12288), dim3(256), 0, stream>>>(x1, x2, x3, xcat);
  k_mgemm<192><<<dim3(512), dim3(256), 0, stream>>>(xcat, c1wT, gpart);
  k_j2<<<dim3(8), dim3(256), 0, stream>>>(gpart, W[23], W[24], gc);
  k_final<<<dim3(1024), dim3(256), 0, stream>>>(xcat, gc, W[25], c2wT, c3wT,
                                                W[27], W[28], W[29], (float*)d_out);
}

// Round 16
// 1698.648 us; speedup vs baseline: 1.0303x; 1.0303x over previous
//
#include <hip/hip_runtime.h>

#define Nn 4096
#define KK 20
#define BN 16384   // B*N, B=4

typedef __attribute__((ext_vector_type(8))) short bf16x8;
typedef __attribute__((ext_vector_type(4))) float f32x4;

__device__ __forceinline__ unsigned short f2bf(float f) {
  unsigned int x = __float_as_uint(f);
  return (unsigned short)((x + 0x7fffu + ((x >> 16) & 1u)) >> 16);
}
__device__ __forceinline__ float bf2f(unsigned short u) {
  return __uint_as_float(((unsigned int)u) << 16);
}

// ---------------- extract pts = x[:,:,:3] ---------------------------------
__global__ void k_pts(const float* __restrict__ x, float* __restrict__ pts) {
  int i = blockIdx.x * 256 + threadIdx.x;
  if (i < BN * 3) {
    int pt = i / 3, c = i - 3 * pt;
    pts[i] = x[pt * 6 + c];
  }
}

// ---------------- weight convert+transpose to bf16 ------------------------
__global__ void k_cvtT(const float* __restrict__ src, unsigned short* __restrict__ dst,
                       int N, int K, int ldn, int row0) {
  int i = blockIdx.x * 256 + threadIdx.x;
  if (i >= N * K) return;
  int n = i / K, k = i - n * K;
  dst[i] = f2bf(src[(size_t)(row0 + k) * ldn + n]);
}

// ---------------- transpose + 3-way bf16 split ----------------------------
__global__ void k_cvtT3(const float* __restrict__ src, unsigned short* __restrict__ h,
                        unsigned short* __restrict__ m, unsigned short* __restrict__ l,
                        int N, int K, int ldn) {
  int i = blockIdx.x * 256 + threadIdx.x;
  if (i >= N * K) return;
  int n = i / K, k = i - n * K;
  float x = src[(size_t)k * ldn + n];
  unsigned short hh = f2bf(x); float xh = bf2f(hh);
  unsigned short mm = f2bf(x - xh); float xm = bf2f(mm);
  unsigned short ll = f2bf(x - xh - xm);
  h[i] = hh; m[i] = mm; l[i] = ll;
}

// ---------------- 3-way bf16 split (row-major passthrough) ----------------
__global__ void k_split3(const float* __restrict__ src, unsigned short* __restrict__ h,
                         unsigned short* __restrict__ m, unsigned short* __restrict__ l, int n) {
  int i = blockIdx.x * 256 + threadIdx.x;
  if (i >= n) return;
  float x = src[i];
  unsigned short hh = f2bf(x); float xh = bf2f(hh);
  unsigned short mm = f2bf(x - xh); float xm = bf2f(mm);
  unsigned short ll = f2bf(x - xh - xm);
  h[i] = hh; m[i] = mm; l[i] = ll;
}

// ---------------- xcat bf16 [pt][192] = [x1|x2|x3] ------------------------
__global__ void k_cat(const float* __restrict__ x1, const float* __restrict__ x2,
                      const float* __restrict__ x3, unsigned short* __restrict__ xcat) {
  int i = blockIdx.x * 256 + threadIdx.x;
  int pt = i / 192, j = i - pt * 192;
  float v = (j < 64) ? x1[pt * 64 + j] : (j < 128 ? x2[pt * 64 + j - 64] : x3[pt * 64 + j - 128]);
  xcat[i] = f2bf(v);
}

// ---------------- maxreduce(8)+bias+relu -> 3-split, rows 4..15 zero ------
__global__ void k_tv3(const float* __restrict__ part, const float* __restrict__ bias,
                      unsigned short* __restrict__ h, unsigned short* __restrict__ m,
                      unsigned short* __restrict__ l) {
  int i = blockIdx.x * 256 + threadIdx.x;   // < 16*1024
  if (i >= 16 * 1024) return;
  int row = i >> 10, col = i & 1023;
  float v = 0.f;
  if (row < 4) {
    float mx = -INFINITY;
#pragma unroll
    for (int s = 0; s < 8; ++s) mx = fmaxf(mx, part[((size_t)row * 8 + s) * 1024 + col]);
    v = fmaxf(mx + bias[col], 0.f);
  }
  unsigned short hh = f2bf(v); float xh = bf2f(hh);
  unsigned short mm = f2bf(v - xh); float xm = bf2f(mm);
  unsigned short ll = f2bf(v - xh - xm);
  h[i] = hh; m[i] = mm; l[i] = ll;
}

// ---------------- zero-padded 3-split of [rows][cols] to [16][cols] -------
__global__ void k_pad3(const float* __restrict__ src, int rows, int cols,
                       unsigned short* __restrict__ h, unsigned short* __restrict__ m,
                       unsigned short* __restrict__ l) {
  int i = blockIdx.x * 256 + threadIdx.x;
  if (i >= 16 * cols) return;
  int row = i / cols, col = i - row * cols;
  float v = (row < rows) ? src[(size_t)row * cols + col] : 0.f;
  unsigned short hh = f2bf(v); float xh = bf2f(hh);
  unsigned short mm = f2bf(v - xh); float xm = bf2f(mm);
  unsigned short ll = f2bf(v - xh - xm);
  h[i] = hh; m[i] = mm; l[i] = ll;
}

// ---------------- small MFMA GEMM: out[4][N] = A[4pad16][K] @ B[N][K]^T ---
template <int N, int K, bool RELU>
__global__ __launch_bounds__(256) void k_gemmS(const unsigned short* __restrict__ Ah,
                                               const unsigned short* __restrict__ Am,
                                               const unsigned short* __restrict__ Al,
                                               const unsigned short* __restrict__ Bh,
                                               const unsigned short* __restrict__ Bm,
                                               const unsigned short* __restrict__ Bl,
                                               const float* __restrict__ bias,
                                               float* __restrict__ outp) {
  constexpr int KS = K / 32;
  int t = threadIdx.x;
  int wv = t >> 6, lane = t & 63;
  int quad = lane >> 4, l16 = lane & 15;
  int col = blockIdx.x * 64 + wv * 16 + l16;
  size_t wo = (size_t)col * K + quad * 8;
  size_t ao = (size_t)l16 * K + quad * 8;
  f32x4 acc = {0.f, 0.f, 0.f, 0.f};
#pragma unroll 4
  for (int s = 0; s < KS; ++s) {
    bf16x8 xh = *(const bf16x8*)(Ah + ao + s * 32);
    bf16x8 xm = *(const bf16x8*)(Am + ao + s * 32);
    bf16x8 xl = *(const bf16x8*)(Al + ao + s * 32);
    bf16x8 wh = *(const bf16x8*)(Bh + wo + s * 32);
    bf16x8 wm = *(const bf16x8*)(Bm + wo + s * 32);
    bf16x8 wl = *(const bf16x8*)(Bl + wo + s * 32);
    acc = __builtin_amdgcn_mfma_f32_16x16x32_bf16(xh, wh, acc, 0, 0, 0);
    acc = __builtin_amdgcn_mfma_f32_16x16x32_bf16(xh, wm, acc, 0, 0, 0);
    acc = __builtin_amdgcn_mfma_f32_16x16x32_bf16(xm, wh, acc, 0, 0, 0);
    acc = __builtin_amdgcn_mfma_f32_16x16x32_bf16(xh, wl, acc, 0, 0, 0);
    acc = __builtin_amdgcn_mfma_f32_16x16x32_bf16(xl, wh, acc, 0, 0, 0);
    acc = __builtin_amdgcn_mfma_f32_16x16x32_bf16(xm, wm, acc, 0, 0, 0);
  }
  if (quad == 0) {
    float bb = bias ? bias[col] : 0.f;
#pragma unroll
    for (int r = 0; r < 4; ++r) {
      float v = acc[r] + bb;
      if (RELU) v = fmaxf(v, 0.f);
      outp[(size_t)r * N + col] = v;
    }
  }
}

// ---------------- fc3 (256->9) + apply p = pts @ xf -----------------------
__global__ __launch_bounds__(256) void k_fc3p(const float* __restrict__ h2, const float* __restrict__ txw,
                                              const float* __restrict__ txb, const float* __restrict__ pts,
                                              float* __restrict__ p) {
  __shared__ float sh2[256];
  __shared__ float sxf[9];
  int t = threadIdx.x;
  int b = blockIdx.x;
  sh2[t] = h2[(size_t)b * 256 + t];
  __syncthreads();
  if (t < 9) {
    float acc = txb[t];
    for (int j = 0; j < 256; ++j) acc = fmaf(sh2[j], txw[j * 9 + t], acc);
    sxf[t] = acc;
  }
  __syncthreads();
  for (int n = t; n < Nn; n += 256) {
    const float* pr = pts + ((size_t)b * Nn + n) * 3;
    float a0 = pr[0], a1 = pr[1], a2 = pr[2];
    float* po = p + ((size_t)b * Nn + n) * 3;
#pragma unroll
    for (int d = 0; d < 3; ++d) po[d] = a0 * sxf[d] + a1 * sxf[3 + d] + a2 * sxf[6 + d];
  }
}

// ---------------- shared distance helper ----------------------------------
__device__ __forceinline__ float dist4(const float4* __restrict__ tile4, int c,
                                       float qx, float qy, float qz, float qsq) {
  float4 v = tile4[c];
  float dot = fmaf(qx, v.x, fmaf(qy, v.y, qz * v.z));
  return 2.0f * dot - qsq - v.w;
}

// ---------------- kNN, C=3: 1024 thr = 16 waves = 16 queries --------------
__global__ __launch_bounds__(1024) void k_knn3(const float* __restrict__ src, int* __restrict__ idx) {
  __shared__ float4 tile4[Nn];   // 64 KB
  int t = threadIdx.x;
  int wave = t >> 6, lane = t & 63;
  int g = blockIdx.x * 16 + wave;
  int b = g >> 12, n = g & (Nn - 1);
  const float* base = src + (size_t)b * Nn * 3;
  for (int e = t; e < Nn; e += 1024) {
    float x = base[e * 3], y = base[e * 3 + 1], z = base[e * 3 + 2];
    tile4[e] = make_float4(x, y, z, fmaf(x, x, fmaf(y, y, z * z)));
  }
  __syncthreads();
  float4 q4 = tile4[n];
  float qx = q4.x, qy = q4.y, qz = q4.z, qsq = q4.w;
  float m1 = -INFINITY, m2 = -INFINITY, m3 = -INFINITY;
  int t1 = 0, t2 = 0, t3 = 0;
#pragma unroll 4
  for (int tt = 0; tt < 64; ++tt) {
    float dd = dist4(tile4, (tt << 6) + lane, qx, qy, qz, qsq);
    if (dd > m3) {
      if (dd > m1) { m3 = m2; t3 = t2; m2 = m1; t2 = t1; m1 = dd; t1 = tt; }
      else if (dd > m2) { m3 = m2; t3 = t2; m2 = dd; t2 = tt; }
      else { m3 = dd; t3 = tt; }
    }
  }
  unsigned long long removed = 0ull;
  int cnt = 3;
  int sel = 0;
#pragma unroll 1
  for (int k = 0; k < 20; ++k) {
    float v = m1; int ci = (t1 << 6) | lane;
#pragma unroll
    for (int off = 32; off; off >>= 1) {
      float ov = __shfl_xor(v, off, 64);
      int   oi = __shfl_xor(ci, off, 64);
      if (ov > v || (ov == v && oi < ci)) { v = ov; ci = oi; }
    }
    if (k == lane) sel = ci;
    if ((ci & 63) == lane && (ci >> 6) == t1) {
      removed |= 1ull << t1;
      if (cnt > 1) { m1 = m2; t1 = t2; m2 = m3; t2 = t3; --cnt; }
      else {
        m1 = -INFINITY; m2 = -INFINITY; m3 = -INFINITY; t1 = 0; t2 = 0; t3 = 0;
#pragma unroll 1
        for (int tt = 0; tt < 64; ++tt) {
          if ((removed >> tt) & 1ull) continue;
          float dd = dist4(tile4, (tt << 6) + lane, qx, qy, qz, qsq);
          if (dd > m3) {
            if (dd > m1) { m3 = m2; t3 = t2; m2 = m1; t2 = t1; m1 = dd; t1 = tt; }
            else if (dd > m2) { m3 = m2; t3 = t2; m2 = dd; t2 = tt; }
            else { m3 = dd; t3 = tt; }
          }
        }
        cnt = 3;
      }
    }
  }
  if (lane < 20) idx[(size_t)g * KK + lane] = sel;
}

// ---------------- sq norms ------------------------------------------------
__global__ void k_sqnorm(const float* __restrict__ src, float* __restrict__ out) {
  int g = blockIdx.x * 256 + threadIdx.x;
  if (g >= BN) return;
  const float4* r = (const float4*)(src + (size_t)g * 64);
  float s = 0.f;
#pragma unroll
  for (int j = 0; j < 16; ++j) { float4 v = r[j]; s += v.x * v.x + v.y * v.y + v.z * v.z + v.w * v.w; }
  out[g] = s;
}

// ---------------- distance GEMM via 3-split bf16 MFMA ---------------------
__global__ __launch_bounds__(256) void k_dist3s(const unsigned short* __restrict__ Xh,
                                                const unsigned short* __restrict__ Xm,
                                                const unsigned short* __restrict__ Xl,
                                                const float* __restrict__ sq,
                                                int b, float* __restrict__ D) {
  int t = threadIdx.x;
  int wv = t >> 6, lane = t & 63;
  int quad = lane >> 4, l16 = lane & 15;
  int wx = wv & 1, wy = wv >> 1;
  int bx = blockIdx.x & 63, by = blockIdx.x >> 6;
  const size_t base = (size_t)b * Nn * 64;
  int ra0 = by * 64 + wy * 32;
  int cb0 = bx * 64 + wx * 32;
  f32x4 acc[2][2];
  f32x4 zz = {0.f, 0.f, 0.f, 0.f};
#pragma unroll
  for (int i = 0; i < 2; ++i)
#pragma unroll
    for (int j = 0; j < 2; ++j) acc[i][j] = zz;
#pragma unroll
  for (int ks = 0; ks < 2; ++ks) {
    int ko = ks * 32 + quad * 8;
    bf16x8 ah[2], am[2], al[2], bh[2], bm[2], bl[2];
#pragma unroll
    for (int ti = 0; ti < 2; ++ti) {
      size_t ra = base + (size_t)(ra0 + ti * 16 + l16) * 64 + ko;
      ah[ti] = *(const bf16x8*)(Xh + ra);
      am[ti] = *(const bf16x8*)(Xm + ra);
      al[ti] = *(const bf16x8*)(Xl + ra);
      size_t rb = base + (size_t)(cb0 + ti * 16 + l16) * 64 + ko;
      bh[ti] = *(const bf16x8*)(Xh + rb);
      bm[ti] = *(const bf16x8*)(Xm + rb);
      bl[ti] = *(const bf16x8*)(Xl + rb);
    }
#pragma unroll
    for (int ti = 0; ti < 2; ++ti)
#pragma unroll
      for (int tj = 0; tj < 2; ++tj) {
        f32x4 a = acc[ti][tj];
        a = __builtin_amdgcn_mfma_f32_16x16x32_bf16(ah[ti], bh[tj], a, 0, 0, 0);
        a = __builtin_amdgcn_mfma_f32_16x16x32_bf16(ah[ti], bm[tj], a, 0, 0, 0);
        a = __builtin_amdgcn_mfma_f32_16x16x32_bf16(am[ti], bh[tj], a, 0, 0, 0);
        a = __builtin_amdgcn_mfma_f32_16x16x32_bf16(ah[ti], bl[tj], a, 0, 0, 0);
        a = __builtin_amdgcn_mfma_f32_16x16x32_bf16(al[ti], bh[tj], a, 0, 0, 0);
        a = __builtin_amdgcn_mfma_f32_16x16x32_bf16(am[ti], bm[tj], a, 0, 0, 0);
        acc[ti][tj] = a;
      }
  }
  const float* sqb = sq + b * Nn;
#pragma unroll
  for (int ti = 0; ti < 2; ++ti) {
    int row0 = ra0 + ti * 16 + quad * 4;
#pragma unroll
    for (int tj = 0; tj < 2; ++tj) {
      int col = cb0 + tj * 16 + l16;
      float sqc = sqb[col];
#pragma unroll
      for (int r = 0; r < 4; ++r)
        D[(size_t)(row0 + r) * 4096 + col] = 2.0f * acc[ti][tj][r] - sqb[row0 + r] - sqc;
    }
  }
}

// ---------------- top-20 over D rows (d[64] cached in VGPRs) --------------
__device__ __forceinline__ int gi_map(int tt, int lane) {
  return ((tt >> 2) << 8) | (lane << 2) | (tt & 3);
}
__device__ __forceinline__ void topk_select2(const float (&d)[64], float m1, int t1, float m2, int t2,
                                             int lane, int* __restrict__ op) {
  unsigned long long removed = 0ull;
  bool have2 = true;
  int sel = 0;
#pragma unroll 1
  for (int k = 0; k < 20; ++k) {
    float v = m1; int ci = gi_map(t1, lane);
#pragma unroll
    for (int off = 32; off; off >>= 1) {
      float ov = __shfl_xor(v, off, 64);
      int   oi = __shfl_xor(ci, off, 64);
      if (ov > v || (ov == v && oi < ci)) { v = ov; ci = oi; }
    }
    if (k == lane) sel = ci;
    if (ci == gi_map(t1, lane)) {
      removed |= 1ull << t1;
      if (have2) { m1 = m2; t1 = t2; have2 = false; }
      else {
        m1 = -INFINITY; t1 = 0; m2 = -INFINITY; t2 = 0;
#pragma unroll
        for (int tt = 0; tt < 64; ++tt) {
          if (!((removed >> tt) & 1ull)) {
            float dv = d[tt];
            if (dv > m1) { m2 = m1; t2 = t1; m1 = dv; t1 = tt; }
            else if (dv > m2) { m2 = dv; t2 = tt; }
          }
        }
        have2 = true;
      }
    }
  }
  if (lane < 20) op[lane] = sel;
}

__global__ __launch_bounds__(256) void k_sel(const float* __restrict__ D, int b, int* __restrict__ idx) {
  int t = threadIdx.x;
  int wave = t >> 6, lane = t & 63;
  int q = blockIdx.x * 4 + wave;
  const float* row = D + (size_t)q * 4096;
  float d[64];
  float m1 = -INFINITY, m2 = -INFINITY; int t1 = 0, t2 = 0;
#pragma unroll
  for (int i = 0; i < 16; ++i) {
    float4 v = *(const float4*)(row + i * 256 + lane * 4);
    float vv[4] = {v.x, v.y, v.z, v.w};
#pragma unroll
    for (int j = 0; j < 4; ++j) {
      int tt = i * 4 + j;
      float dd = vv[j];
      d[tt] = dd;
      if (dd > m1) { m2 = m1; t2 = t1; m1 = dd; t1 = tt; }
      else if (dd > m2) { m2 = dd; t2 = tt; }
    }
  }
  topk_select2(d, m1, t1, m2, t2, lane, idx + (size_t)(b * Nn + q) * KK);
}

// ---------------- u/v from pts (6->64 conv1 factorized) -------------------
__global__ __launch_bounds__(256) void k_uv3(const float* __restrict__ pts, const float* __restrict__ w1,
                                             const float* __restrict__ b1, float* __restrict__ uvb) {
  __shared__ float sw[384];
  __shared__ float sb[64];
  int t = threadIdx.x;
  for (int e = t; e < 384; e += 256) sw[e] = w1[e];
  if (t < 64) sb[t] = b1[t];
  __syncthreads();
  int pl = t >> 6, c = t & 63;
  int p = blockIdx.x * 4 + pl;
  const float* pr = pts + (size_t)p * 3;
  float x0 = pr[0], x1 = pr[1], x2 = pr[2];
  float wb0 = sw[192 + c], wb1 = sw[256 + c], wb2 = sw[320 + c];
  float v = x0 * wb0 + x1 * wb1 + x2 * wb2;
  float u = sb[c] + x0 * (sw[c] - wb0) + x1 * (sw[64 + c] - wb1) + x2 * (sw[128 + c] - wb2);
  uvb[(size_t)p * 128 + c] = u;
  uvb[(size_t)p * 128 + 64 + c] = v;
}

// ---------------- prep: Md[64][128] = [Wa-Wb | Wb] from 128x64 w1 ---------
__global__ void k_prepD(const float* __restrict__ w1, float* __restrict__ Md) {
  int i = blockIdx.x * 256 + threadIdx.x;
  if (i >= 8192) return;
  int j = i >> 7, c = i & 127;
  Md[i] = (c < 64) ? (w1[j * 64 + c] - w1[(64 + j) * 64 + c]) : w1[(64 + j) * 64 + (c - 64)];
}

// ---------------- uv = x @ Md (+bias on u half) ---------------------------
__global__ __launch_bounds__(256) void k_uv(const float* __restrict__ x2, const float* __restrict__ Md,
                                            const float* __restrict__ bias, float* __restrict__ uv) {
  __shared__ float sM[8192];     // 64x128
  __shared__ float sx[64 * 68];
  int t = threadIdx.x;
  for (int e = t; e < 8192; e += 256) sM[e] = Md[e];
  int p0 = blockIdx.x * 64;
  for (int e = t; e < 1024; e += 256) {
    int r = e >> 4, c4 = e & 15;
    *(float4*)(sx + r * 68 + c4 * 4) = *(const float4*)(x2 + (size_t)(p0 + r) * 64 + c4 * 4);
  }
  __syncthreads();
  int c = t & 127, rg = t >> 7;
  float badd = (c < 64) ? bias[c] : 0.f;
  float accv[32];
#pragma unroll
  for (int r = 0; r < 32; ++r) accv[r] = 0.f;
#pragma unroll
  for (int jc = 0; jc < 8; ++jc) {
    float mreg[8];
#pragma unroll
    for (int q = 0; q < 8; ++q) mreg[q] = sM[(jc * 8 + q) * 128 + c];
#pragma unroll
    for (int r = 0; r < 32; ++r) {
      const float* xr = sx + (rg * 32 + r) * 68 + jc * 8;
      float4 a = *(const float4*)xr, bb = *(const float4*)(xr + 4);
      float s = accv[r];
      s = fmaf(a.x, mreg[0], s); s = fmaf(a.y, mreg[1], s);
      s = fmaf(a.z, mreg[2], s); s = fmaf(a.w, mreg[3], s);
      s = fmaf(bb.x, mreg[4], s); s = fmaf(bb.y, mreg[5], s);
      s = fmaf(bb.z, mreg[6], s); s = fmaf(bb.w, mreg[7], s);
      accv[r] = s;
    }
  }
#pragma unroll
  for (int r = 0; r < 32; ++r)
    uv[(size_t)(p0 + rg * 32 + r) * 128 + c] = accv[r] + badd;
}

// ---------------- per-edge conv2 via 3-split MFMA + max over edges --------
template <int NOUT>
__global__ __launch_bounds__(256, 4) void k_econv(const float* __restrict__ uv,
                                                  const int* __restrict__ idx,
                                                  const unsigned short* __restrict__ W2h,
                                                  const unsigned short* __restrict__ W2m,
                                                  const unsigned short* __restrict__ W2l,
                                                  const float* __restrict__ b2,
                                                  float* __restrict__ outp) {
  __shared__ unsigned short y3[4][3][20 * 72];        // 34560 B
  __shared__ __align__(16) unsigned short zrow[72];   // shared zero row
  int t = threadIdx.x;
  int wv = t >> 6, lane = t & 63;
  int quad = lane >> 4, l16 = lane & 15;
  int p = blockIdx.x * 4 + wv;
  size_t nbase = (size_t)(p >> 12) * Nn;
  const int* ip = idx + (size_t)p * KK;
  float u = uv[(size_t)p * 128 + lane];
  if (t < 72) zrow[t] = 0;
  unsigned short* yh = y3[wv][0];
  unsigned short* ym = y3[wv][1];
  unsigned short* yl = y3[wv][2];
  float vv[20];
#pragma unroll
  for (int k = 0; k < 20; ++k) {
    int nb = ip[k];
    vv[k] = uv[(nbase + nb) * 128 + 64 + lane];
  }
#pragma unroll
  for (int k = 0; k < 20; ++k) {
    float y = fmaxf(u + vv[k], 0.f);
    unsigned short hh = f2bf(y); float fh = bf2f(hh);
    unsigned short mm = f2bf(y - fh); float fm = bf2f(mm);
    unsigned short ll = f2bf(y - fh - fm);
    yh[k * 72 + lane] = hh;
    ym[k * 72 + lane] = mm;
    yl[k * 72 + lane] = ll;
  }
  __syncthreads();
  bf16x8 af[2][2][3];
#pragma unroll
  for (int mt = 0; mt < 2; ++mt)
#pragma unroll
    for (int ks = 0; ks < 2; ++ks) {
      int row = mt * 16 + l16;
      int ko = ks * 32 + quad * 8;
      const unsigned short* ph = (row < 20) ? (yh + row * 72) : zrow;
      const unsigned short* pm = (row < 20) ? (ym + row * 72) : zrow;
      const unsigned short* pl = (row < 20) ? (yl + row * 72) : zrow;
      af[mt][ks][0] = *(const bf16x8*)(ph + ko);
      af[mt][ks][1] = *(const bf16x8*)(pm + ko);
      af[mt][ks][2] = *(const bf16x8*)(pl + ko);
    }
#pragma unroll 1
  for (int nt = 0; nt < NOUT / 16; ++nt) {
    int col = nt * 16 + l16;
    f32x4 a0 = {0.f, 0.f, 0.f, 0.f}, a1 = {0.f, 0.f, 0.f, 0.f};
#pragma unroll
    for (int ks = 0; ks < 2; ++ks) {
      size_t wo = (size_t)col * 64 + ks * 32 + quad * 8;
      bf16x8 wh = *(const bf16x8*)(W2h + wo);
      bf16x8 wm = *(const bf16x8*)(W2m + wo);
      bf16x8 wl = *(const bf16x8*)(W2l + wo);
      a0 = __builtin_amdgcn_mfma_f32_16x16x32_bf16(af[0][ks][0], wh, a0, 0, 0, 0);
      a0 = __builtin_amdgcn_mfma_f32_16x16x32_bf16(af[0][ks][0], wm, a0, 0, 0, 0);
      a0 = __builtin_amdgcn_mfma_f32_16x16x32_bf16(af[0][ks][1], wh, a0, 0, 0, 0);
      a0 = __builtin_amdgcn_mfma_f32_16x16x32_bf16(af[0][ks][0], wl, a0, 0, 0, 0);
      a0 = __builtin_amdgcn_mfma_f32_16x16x32_bf16(af[0][ks][2], wh, a0, 0, 0, 0);
      a0 = __builtin_amdgcn_mfma_f32_16x16x32_bf16(af[0][ks][1], wm, a0, 0, 0, 0);
      a1 = __builtin_amdgcn_mfma_f32_16x16x32_bf16(af[1][ks][0], wh, a1, 0, 0, 0);
      a1 = __builtin_amdgcn_mfma_f32_16x16x32_bf16(af[1][ks][0], wm, a1, 0, 0, 0);
      a1 = __builtin_amdgcn_mfma_f32_16x16x32_bf16(af[1][ks][1], wh, a1, 0, 0, 0);
      a1 = __builtin_amdgcn_mfma_f32_16x16x32_bf16(af[1][ks][0], wl, a1, 0, 0, 0);
      a1 = __builtin_amdgcn_mfma_f32_16x16x32_bf16(af[1][ks][2], wh, a1, 0, 0, 0);
      a1 = __builtin_amdgcn_mfma_f32_16x16x32_bf16(af[1][ks][1], wm, a1, 0, 0, 0);
    }
    float m0 = fmaxf(fmaxf(a0[0], a0[1]), fmaxf(a0[2], a0[3]));
    float m1v = (quad == 0) ? fmaxf(fmaxf(a1[0], a1[1]), fmaxf(a1[2], a1[3])) : -INFINITY;
    float m = fmaxf(m0, m1v);
    m = fmaxf(m, __shfl_xor(m, 16, 64));
    m = fmaxf(m, __shfl_xor(m, 32, 64));
    if (quad == 0) outp[(size_t)p * NOUT + col] = fmaxf(m + b2[col], 0.f);
  }
}

// ---------------- x3 = relu(u + max_k v_nk)  (bias folded into u) ---------
__global__ __launch_bounds__(256) void k_gmax(const float* __restrict__ uv, const int* __restrict__ idx,
                                              float* __restrict__ x3) {
  __shared__ int sidx[4][20];
  int t = threadIdx.x;
  int pl = t >> 6, c = t & 63;
  int p0 = blockIdx.x * 4;
  if (t < 80) sidx[t / 20][t % 20] = idx[(size_t)(p0 + t / 20) * KK + (t % 20)];
  __syncthreads();
  int p = p0 + pl;
  size_t nbase = (size_t)(p >> 12) * Nn;
  float u = uv[(size_t)p * 128 + c];
  float m = -INFINITY;
#pragma unroll
  for (int k = 0; k < 20; ++k) m = fmaxf(m, uv[(nbase + sidx[pl][k]) * 128 + 64 + c]);
  x3[(size_t)p * 64 + c] = fmaxf(u + m, 0.f);
}

// ---------------- MFMA max-GEMM (bf16, post-kNN path) ---------------------
template <int K>
__global__ __launch_bounds__(256) void k_mgemm(const unsigned short* __restrict__ A,
                                               const unsigned short* __restrict__ WT,
                                               float* __restrict__ outp) {
  constexpr int KS = K / 32;
  int t = threadIdx.x;
  int wv = t >> 6, lane = t & 63;
  int quad = lane >> 4, l16 = lane & 15;
  int blk = blockIdx.x;
  int b = blk >> 7, cb = (blk >> 3) & 15, ns = blk & 7;
  int n0 = cb * 64 + wv * 16;
  bf16x8 bfr[KS];
  const unsigned short* wrow = WT + (size_t)(n0 + l16) * K + quad * 8;
#pragma unroll
  for (int s = 0; s < KS; ++s) bfr[s] = *(const bf16x8*)(wrow + s * 32);
  const unsigned short* Ab = A + ((size_t)b * Nn + ns * 512 + l16) * K + quad * 8;
  float rmax = -INFINITY;
#pragma unroll 2
  for (int mt = 0; mt < 32; ++mt) {
    const unsigned short* ar = Ab + (size_t)mt * 16 * K;
    f32x4 acc = {0.f, 0.f, 0.f, 0.f};
#pragma unroll
    for (int s = 0; s < KS; ++s) {
      bf16x8 af = *(const bf16x8*)(ar + s * 32);
      acc = __builtin_amdgcn_mfma_f32_16x16x32_bf16(af, bfr[s], acc, 0, 0, 0);
    }
    rmax = fmaxf(rmax, fmaxf(fmaxf(acc[0], acc[1]), fmaxf(acc[2], acc[3])));
  }
  rmax = fmaxf(rmax, __shfl_xor(rmax, 16, 64));
  rmax = fmaxf(rmax, __shfl_xor(rmax, 32, 64));
  if (quad == 0) outp[((size_t)b * 8 + ns) * 1024 + n0 + l16] = rmax;
}

// ---------------- MFMA max-GEMM, 3-split exact (t128 @ w3) ----------------
template <int K>
__global__ __launch_bounds__(256) void k_mgemm3s(const unsigned short* __restrict__ Ah,
                                                 const unsigned short* __restrict__ Am,
                                                 const unsigned short* __restrict__ Al,
                                                 const unsigned short* __restrict__ Bh,
                                                 const unsigned short* __restrict__ Bm,
                                                 const unsigned short* __restrict__ Bl,
                                                 float* __restrict__ outp) {
  constexpr int KS = K / 32;
  int t = threadIdx.x;
  int wv = t >> 6, lane = t & 63;
  int quad = lane >> 4, l16 = lane & 15;
  int blk = blockIdx.x;
  int b = blk >> 7, cb = (blk >> 3) & 15, ns = blk & 7;
  int n0 = cb * 64 + wv * 16;
  bf16x8 wh[KS], wm[KS], wl[KS];
  size_t wo = (size_t)(n0 + l16) * K + quad * 8;
#pragma unroll
  for (int s = 0; s < KS; ++s) {
    wh[s] = *(const bf16x8*)(Bh + wo + s * 32);
    wm[s] = *(const bf16x8*)(Bm + wo + s * 32);
    wl[s] = *(const bf16x8*)(Bl + wo + s * 32);
  }
  size_t ao = ((size_t)b * Nn + ns * 512 + l16) * K + quad * 8;
  float rmax = -INFINITY;
#pragma unroll 1
  for (int mt = 0; mt < 32; ++mt) {
    size_t ar = ao + (size_t)mt * 16 * K;
    f32x4 acc = {0.f, 0.f, 0.f, 0.f};
#pragma unroll
    for (int s = 0; s < KS; ++s) {
      bf16x8 xh = *(const bf16x8*)(Ah + ar + s * 32);
      bf16x8 xm = *(const bf16x8*)(Am + ar + s * 32);
      bf16x8 xl = *(const bf16x8*)(Al + ar + s * 32);
      acc = __builtin_amdgcn_mfma_f32_16x16x32_bf16(xh, wh[s], acc, 0, 0, 0);
      acc = __builtin_amdgcn_mfma_f32_16x16x32_bf16(xh, wm[s], acc, 0, 0, 0);
      acc = __builtin_amdgcn_mfma_f32_16x16x32_bf16(xm, wh[s], acc, 0, 0, 0);
      acc = __builtin_amdgcn_mfma_f32_16x16x32_bf16(xh, wl[s], acc, 0, 0, 0);
      acc = __builtin_amdgcn_mfma_f32_16x16x32_bf16(xl, wh[s], acc, 0, 0, 0);
      acc = __builtin_amdgcn_mfma_f32_16x16x32_bf16(xm, wm[s], acc, 0, 0, 0);
    }
    rmax = fmaxf(rmax, fmaxf(fmaxf(acc[0], acc[1]), fmaxf(acc[2], acc[3])));
  }
  rmax = fmaxf(rmax, __shfl_xor(rmax, 16, 64));
  rmax = fmaxf(rmax, __shfl_xor(rmax, 32, 64));
  if (quad == 0) outp[((size_t)b * 8 + ns) * 1024 + n0 + l16] = rmax;
}

// ---------------- fused MFMA head: 192->512->256->2 per 16 points ---------
__global__ __launch_bounds__(256) void k_final(const unsigned short* __restrict__ xcat,
                                               const float* __restrict__ gc,
                                               const float* __restrict__ c2b,
                                               const unsigned short* __restrict__ c2wT,
                                               const unsigned short* __restrict__ c3wT,
                                               const float* __restrict__ c3b,
                                               const float* __restrict__ c4w, const float* __restrict__ c4b,
                                               float* __restrict__ out) {
  __shared__ unsigned short z5[16 * 520];
  __shared__ float z2[16 * 260];
  int t = threadIdx.x;
  int wv = t >> 6, lane = t & 63;
  int quad = lane >> 4, l16 = lane & 15;
  int p0 = blockIdx.x * 16;
  int b = p0 >> 12;
  bf16x8 a1[6];
  const unsigned short* ar = xcat + (size_t)(p0 + l16) * 192 + quad * 8;
#pragma unroll
  for (int s = 0; s < 6; ++s) a1[s] = *(const bf16x8*)(ar + s * 32);
#pragma unroll 1
  for (int ntw = 0; ntw < 8; ++ntw) {
    int col = wv * 128 + ntw * 16 + l16;
    float bias = gc[(size_t)b * 512 + col] + c2b[col];
    f32x4 acc = {bias, bias, bias, bias};
    const unsigned short* wr = c2wT + (size_t)col * 192 + quad * 8;
#pragma unroll
    for (int s = 0; s < 6; ++s) {
      bf16x8 bfr = *(const bf16x8*)(wr + s * 32);
      acc = __builtin_amdgcn_mfma_f32_16x16x32_bf16(a1[s], bfr, acc, 0, 0, 0);
    }
#pragma unroll
    for (int r = 0; r < 4; ++r)
      z5[(quad * 4 + r) * 520 + col] = f2bf(fmaxf(acc[r], 0.f));
  }
  __syncthreads();
  bf16x8 a2[16];
#pragma unroll
  for (int s = 0; s < 16; ++s) a2[s] = *(const bf16x8*)(z5 + l16 * 520 + s * 32 + quad * 8);
#pragma unroll 1
  for (int ntw = 0; ntw < 4; ++ntw) {
    int col = wv * 64 + ntw * 16 + l16;
    float bias = c3b[col];
    f32x4 acc = {bias, bias, bias, bias};
    const unsigned short* wr = c3wT + (size_t)col * 512 + quad * 8;
#pragma unroll
    for (int s = 0; s < 16; ++s) {
      bf16x8 bfr = *(const bf16x8*)(wr + s * 32);
      acc = __builtin_amdgcn_mfma_f32_16x16x32_bf16(a2[s], bfr, acc, 0, 0, 0);
    }
#pragma unroll
    for (int r = 0; r < 4; ++r)
      z2[(quad * 4 + r) * 260 + col] = fmaxf(acc[r], 0.f);
  }
  __syncthreads();
  if (t < 32) {
    int m = t >> 1, e = t & 1;
    float acc = c4b[e];
    const float* zr = z2 + m * 260;
    for (int j = 0; j < 256; ++j) acc = fmaf(zr[j], c4w[j * 2 + e], acc);
    out[(size_t)(p0 + m) * 2 + e] = acc;
  }
}

// ===========================================================================
extern "C" void kernel_launch(void* const* d_in, const int* in_sizes, int n_in,
                              void* d_out, int out_size, void* d_ws, size_t ws_size,
                              hipStream_t stream) {
  const float* xin = (const float*)d_in[0];
  const float* W[30];
  for (int i = 0; i < 30; ++i) W[i] = (const float*)d_in[i + 1];

  float* ws = (float*)d_ws;
  size_t off = 0;
  float* pts   = ws + off; off += (size_t)BN * 3;
  float* p     = ws + off; off += (size_t)BN * 3;
  int*   idx   = (int*)(ws + off); off += (size_t)BN * KK;
  float* sq    = ws + off; off += BN;
  float* t128  = ws + off; off += (size_t)BN * 128;
  float* dpart = ws + off; off += 4 * 8 * 1024;
  float* h1    = ws + off; off += 4 * 512;
  float* h2b   = ws + off; off += 4 * 256;
  float* x1    = ws + off; off += (size_t)BN * 64;
  float* x2    = ws + off; off += (size_t)BN * 64;
  float* x3    = ws + off; off += (size_t)BN * 64;
  float* gpart = ws + off; off += 4 * 8 * 1024;
  float* gc    = ws + off; off += 4 * 512;
  float* uvb   = ws + off; off += (size_t)BN * 128;
  unsigned short* xcat = (unsigned short*)(ws + off); off += (size_t)BN * 96;
  unsigned short* c1wT = (unsigned short*)(ws + off); off += 98304;
  unsigned short* c2wT = (unsigned short*)(ws + off); off += 49152;
  unsigned short* c3wT = (unsigned short*)(ws + off); off += 65536;
  unsigned short* w3Th = (unsigned short*)(ws + off); off += 65536;
  unsigned short* w3Tm = (unsigned short*)(ws + off); off += 65536;
  unsigned short* w3Tl = (unsigned short*)(ws + off); off += 65536;
  unsigned short* tw2h = (unsigned short*)(ws + off); off += 4096;
  unsigned short* tw2m = (unsigned short*)(ws + off); off += 4096;
  unsigned short* tw2l = (unsigned short*)(ws + off); off += 4096;
  unsigned short* e1h  = (unsigned short*)(ws + off); off += 2048;
  unsigned short* e1m  = (unsigned short*)(ws + off); off += 2048;
  unsigned short* e1l  = (unsigned short*)(ws + off); off += 2048;
  unsigned short* e2h  = (unsigned short*)(ws + off); off += 2048;
  unsigned short* e2m  = (unsigned short*)(ws + off); off += 2048;
  unsigned short* e2l  = (unsigned short*)(ws + off); off += 2048;
  unsigned short* xsh  = (unsigned short*)(ws + off); off += 524288;
  unsigned short* xsm  = (unsigned short*)(ws + off); off += 524288;
  unsigned short* xsl  = (unsigned short*)(ws + off); off += 524288;
  float* MdC   = ws + off; off += 8192;
  float* MdD   = ws + off; off += 8192;
  unsigned short* fw1h = (unsigned short*)(ws + off); off += 262144;  // 512x1024 bf16
  unsigned short* fw1m = (unsigned short*)(ws + off); off += 262144;
  unsigned short* fw1l = (unsigned short*)(ws + off); off += 262144;
  unsigned short* cw2h = (unsigned short*)(ws + off); off += 262144;  // 512x1024 (c2w[:1024])
  unsigned short* cw2m = (unsigned short*)(ws + off); off += 262144;
  unsigned short* cw2l = (unsigned short*)(ws + off); off += 262144;
  unsigned short* fw2h = (unsigned short*)(ws + off); off += 65536;   // 256x512 bf16
  unsigned short* fw2m = (unsigned short*)(ws + off); off += 65536;
  unsigned short* fw2l = (unsigned short*)(ws + off); off += 65536;
  unsigned short* tvh  = (unsigned short*)(ws + off); off += 8192;    // 16x1024 bf16
  unsigned short* tvm  = (unsigned short*)(ws + off); off += 8192;
  unsigned short* tvl  = (unsigned short*)(ws + off); off += 8192;
  unsigned short* h13h = (unsigned short*)(ws + off); off += 4096;    // 16x512 bf16
  unsigned short* h13m = (unsigned short*)(ws + off); off += 4096;
  unsigned short* h13l = (unsigned short*)(ws + off); off += 4096;
  float* Dbuf  = ws + off; off += (size_t)Nn * Nn;
  unsigned short* t3h = (unsigned short*)Dbuf;
  unsigned short* t3m = t3h + (size_t)BN * 128;
  unsigned short* t3l = t3m + (size_t)BN * 128;

  // weight prep
  k_cvtT<<<dim3(768), dim3(256), 0, stream>>>(W[22], c1wT, 1024, 192, 1024, 0);
  k_cvtT<<<dim3(384), dim3(256), 0, stream>>>(W[24], c2wT, 512, 192, 512, 1024);
  k_cvtT<<<dim3(512), dim3(256), 0, stream>>>(W[26], c3wT, 256, 512, 256, 0);
  k_cvtT3<<<dim3(512), dim3(256), 0, stream>>>(W[4], w3Th, w3Tm, w3Tl, 1024, 128, 1024);
  k_cvtT3<<<dim3(32), dim3(256), 0, stream>>>(W[2], tw2h, tw2m, tw2l, 128, 64, 128);
  k_cvtT3<<<dim3(16), dim3(256), 0, stream>>>(W[14], e1h, e1m, e1l, 64, 64, 64);
  k_cvtT3<<<dim3(16), dim3(256), 0, stream>>>(W[18], e2h, e2m, e2l, 64, 64, 64);
  k_cvtT3<<<dim3(2048), dim3(256), 0, stream>>>(W[6], fw1h, fw1m, fw1l, 512, 1024, 512);
  k_cvtT3<<<dim3(2048), dim3(256), 0, stream>>>(W[24], cw2h, cw2m, cw2l, 512, 1024, 512);
  k_cvtT3<<<dim3(512), dim3(256), 0, stream>>>(W[8], fw2h, fw2m, fw2l, 256, 512, 256);
  k_prepD<<<dim3(32), dim3(256), 0, stream>>>(W[16], MdC);
  k_prepD<<<dim3(32), dim3(256), 0, stream>>>(W[20], MdD);

  k_pts<<<dim3(192), dim3(256), 0, stream>>>(xin, pts);

  // stage 1: transform branch
  k_knn3<<<dim3(1024), dim3(1024), 0, stream>>>(pts, idx);
  k_uv3<<<dim3(4096), dim3(256), 0, stream>>>(pts, W[0], W[1], uvb);
  k_econv<128><<<dim3(4096), dim3(256), 0, stream>>>(uvb, idx, tw2h, tw2m, tw2l, W[3], t128);
  k_split3<<<dim3(8192), dim3(256), 0, stream>>>(t128, t3h, t3m, t3l, BN * 128);
  k_mgemm3s<128><<<dim3(512), dim3(256), 0, stream>>>(t3h, t3m, t3l, w3Th, w3Tm, w3Tl, dpart);
  // fc1 via small MFMA: tv = relu(max+tb3) -> h1 = relu(tv@tfw1+tfb1)
  k_tv3<<<dim3(64), dim3(256), 0, stream>>>(dpart, W[5], tvh, tvm, tvl);
  k_gemmS<512, 1024, true><<<dim3(8), dim3(256), 0, stream>>>(tvh, tvm, tvl, fw1h, fw1m, fw1l, W[7], h1);
  // fc2 via small MFMA, then fc3+apply
  k_pad3<<<dim3(32), dim3(256), 0, stream>>>(h1, 4, 512, h13h, h13m, h13l);
  k_gemmS<256, 512, true><<<dim3(4), dim3(256), 0, stream>>>(h13h, h13m, h13l, fw2h, fw2m, fw2l, W[9], h2b);
  k_fc3p<<<dim3(4), dim3(256), 0, stream>>>(h2b, W[10], W[11], pts, p);

  // stage 2
  k_knn3<<<dim3(1024), dim3(1024), 0, stream>>>(p, idx);
  k_uv3<<<dim3(4096), dim3(256), 0, stream>>>(p, W[12], W[13], uvb);
  k_econv<64><<<dim3(4096), dim3(256), 0, stream>>>(uvb, idx, e1h, e1m, e1l, W[15], x1);
  k_sqnorm<<<dim3(64), dim3(256), 0, stream>>>(x1, sq);
  k_split3<<<dim3(4096), dim3(256), 0, stream>>>(x1, xsh, xsm, xsl, BN * 64);
  for (int b = 0; b < 4; ++b) {
    k_dist3s<<<dim3(4096), dim3(256), 0, stream>>>(xsh, xsm, xsl, sq, b, Dbuf);
    k_sel<<<dim3(1024), dim3(256), 0, stream>>>(Dbuf, b, idx);
  }
  k_uv<<<dim3(256), dim3(256), 0, stream>>>(x1, MdC, W[17], uvb);
  k_econv<64><<<dim3(4096), dim3(256), 0, stream>>>(uvb, idx, e2h, e2m, e2l, W[19], x2);
  k_sqnorm<<<dim3(64), dim3(256), 0, stream>>>(x2, sq);
  k_split3<<<dim3(4096), dim3(256), 0, stream>>>(x2, xsh, xsm, xsl, BN * 64);
  for (int b = 0; b < 4; ++b) {
    k_dist3s<<<dim3(4096), dim3(256), 0, stream>>>(xsh, xsm, xsl, sq, b, Dbuf);
    k_sel<<<dim3(1024), dim3(256), 0, stream>>>(Dbuf, b, idx);
  }
  // edgeD via u/v factorization (bias folded into u)
  k_uv<<<dim3(256), dim3(256), 0, stream>>>(x2, MdD, W[21], uvb);
  k_gmax<<<dim3(4096), dim3(256), 0, stream>>>(uvb, idx, x3);

  // stage 3
  k_cat<<<dim3(12288), dim3(256), 0, stream>>>(x1, x2, x3, xcat);
  k_mgemm<192><<<dim3(512), dim3(256), 0, stream>>>(xcat, c1wT, gpart);
  // j2 via small MFMA: g = relu(max+c1b) -> gc = g @ c2w[:1024]
  k_tv3<<<dim3(64), dim3(256), 0, stream>>>(gpart, W[23], tvh, tvm, tvl);
  k_gemmS<512, 1024, false><<<dim3(8), dim3(256), 0, stream>>>(tvh, tvm, tvl, cw2h, cw2m, cw2l, nullptr, gc);
  k_final<<<dim3(1024), dim3(256), 0, stream>>>(xcat, gc, W[25], c2wT, c3wT,
                                                W[27], W[28], W[29], (float*)d_out);
}